// Round 3
// baseline (772.102 us; speedup 1.0000x reference)
//
#include <hip/hip_runtime.h>
#include <hip/hip_bf16.h>

#define N_NODES 100000
#define N_EDGES 1600000
#define IN_C 128
#define HID_C 256
#define OUT_C 128

typedef __attribute__((ext_vector_type(8))) short bf16x8;
typedef __attribute__((ext_vector_type(4))) float f32x4;
typedef __attribute__((ext_vector_type(2))) float f32x2;

static __device__ __forceinline__ short f2bf(float f) {
    union { float f; unsigned u; } x{f};
    unsigned r = (x.u + 0x7fffu + ((x.u >> 16) & 1u)) >> 16;
    return (short)r;
}
static __device__ __forceinline__ f32x2 bfpair(unsigned d) {
    union { unsigned u; float f; } lo, hi;
    lo.u = d << 16;
    hi.u = d & 0xffff0000u;
    return f32x2{lo.f, hi.f};
}

// ================= CSR build =================
__global__ void hist_rank(const int* __restrict__ rows, int* __restrict__ deg,
                          int* __restrict__ rank, int E)
{
    int e = blockIdx.x * blockDim.x + threadIdx.x;
    if (e < E) rank[e] = atomicAdd(&deg[rows[e]], 1);
}

#define SCAN_BLOCK 256
#define SCAN_ELEMS 1024

__global__ __launch_bounds__(SCAN_BLOCK) void scan1(const int* __restrict__ deg,
                                                    int* __restrict__ excl,
                                                    int* __restrict__ bsum, int N)
{
    __shared__ int sh[SCAN_BLOCK];
    int t = threadIdx.x;
    int base = blockIdx.x * SCAN_ELEMS + t * 4;
    int v[4];
    #pragma unroll
    for (int i = 0; i < 4; ++i) {
        int idx = base + i;
        v[i] = (idx < N) ? deg[idx] : 0;
    }
    int s = v[0] + v[1] + v[2] + v[3];
    sh[t] = s;
    __syncthreads();
    for (int d = 1; d < SCAN_BLOCK; d <<= 1) {
        int add = (t >= d) ? sh[t - d] : 0;
        __syncthreads();
        sh[t] += add;
        __syncthreads();
    }
    int p = sh[t] - s;
    #pragma unroll
    for (int i = 0; i < 4; ++i) {
        int idx = base + i;
        if (idx < N) excl[idx] = p;
        p += v[i];
    }
    if (t == SCAN_BLOCK - 1) bsum[blockIdx.x] = sh[t];
}

// scan2 folded in: every block recomputes the (<=128-entry) block-sum prefix in LDS.
__global__ void scan3(int* __restrict__ row_start, const int* __restrict__ bsum,
                      int NB, int N, int E)
{
    __shared__ int pref[128];
    int t = threadIdx.x;
    if (t < 128) pref[t] = (t < NB) ? bsum[t] : 0;
    __syncthreads();
    for (int d = 1; d < 128; d <<= 1) {
        int add = (t < 128 && t >= d) ? pref[t - d] : 0;
        __syncthreads();
        if (t < 128) pref[t] += add;
        __syncthreads();
    }
    int i = blockIdx.x * blockDim.x + t;
    if (i < N) {
        int b = i >> 10;
        row_start[i] += (b == 0) ? 0 : pref[b - 1];
    } else if (i == N) {
        row_start[N] = E;
    }
}

// atomic-free scatter fused with bf16 casts (wave-aligned seam: E % 64 == 0)
__global__ void scatter_cast(const int* __restrict__ rows, const int* __restrict__ cols,
                             const float* __restrict__ vals, const int* __restrict__ row_start,
                             const int* __restrict__ rank, int2* __restrict__ epk, int E,
                             const float* __restrict__ s0, short* __restrict__ d0, int n0,
                             const float* __restrict__ s1, short* __restrict__ d1, int n1,
                             const float* __restrict__ s2, short* __restrict__ d2, int n2,
                             const float* __restrict__ s3, short* __restrict__ d3, int n3)
{
    int idx = blockIdx.x * blockDim.x + threadIdx.x;
    if (idx < E) {
        int pos = row_start[rows[idx]] + rank[idx];
        epk[pos] = int2{cols[idx], __float_as_int(vals[idx])};
    } else {
        int i = (idx - E) * 4;
        int castN = n0 + n1 + n2 + n3;
        if (i >= castN) return;
        const float* s; short* d;
        if (i < n0) { s = s0; d = d0; }
        else if ((i -= n0) < n1) { s = s1; d = d1; }
        else if ((i -= n1) < n2) { s = s2; d = d2; }
        else { i -= n2; s = s3; d = d3; }
        float4 v = *(const float4*)(s + i);
        *(short4*)(d + i) = short4{f2bf(v.x), f2bf(v.y), f2bf(v.z), f2bf(v.w)};
    }
}

// ================= paired gather SpMM =================
// 2 edges per wave-wide load: lanes 0-31 gather edge e0's row, lanes 32-63 edge
// e1's row; both halves cover the SAME channels, folded with one shfl_xor(32)
// at row end. Halves the request count at equal bytes (gather is per-request
// bound: C=128 and C=256 layers measured equal duration at 2x the bytes).
// NU = unsigneds (bf16 pairs) per lane per row-half: C=128 -> 2, C=256 -> 4.
template<int B, int NU>
static __device__ __forceinline__ void pair_batch(
    const unsigned* __restrict__ Hb, const int2* __restrict__ epk,
    int j, bool hi, int loff, f32x2* acc)
{
    int2 ea[B], eb[B];
    #pragma unroll
    for (int b = 0; b < B; ++b) { ea[b] = epk[j + 2 * b]; eb[b] = epk[j + 2 * b + 1]; }
    unsigned g[B][NU];
    #pragma unroll
    for (int b = 0; b < B; ++b) {
        const int col = hi ? eb[b].x : ea[b].x;
        const unsigned* p = Hb + (size_t)col * (32 * NU) + loff;
        if constexpr (NU == 4) {
            uint4 t = *(const uint4*)p;
            g[b][0] = t.x; g[b][1] = t.y; g[b][2] = t.z; g[b][3] = t.w;
        } else {
            uint2 t = *(const uint2*)p;
            g[b][0] = t.x; g[b][1] = t.y;
        }
    }
    #pragma unroll
    for (int b = 0; b < B; ++b) {
        const float v = __int_as_float(hi ? eb[b].y : ea[b].y);
        #pragma unroll
        for (int u = 0; u < NU; ++u) acc[u] += v * bfpair(g[b][u]);
    }
}

template<int NU>
static __device__ __forceinline__ void edge_tail(
    const unsigned* __restrict__ Hb, const int2* __restrict__ epk,
    int j, bool hi, int loff, f32x2* acc)
{
    int2 e = epk[j];
    const unsigned* p = Hb + (size_t)e.x * (32 * NU) + loff;
    unsigned g[NU];
    if constexpr (NU == 4) {
        uint4 t = *(const uint4*)p;
        g[0] = t.x; g[1] = t.y; g[2] = t.z; g[3] = t.w;
    } else {
        uint2 t = *(const uint2*)p;
        g[0] = t.x; g[1] = t.y;
    }
    const float v = hi ? 0.f : __int_as_float(e.y);
    #pragma unroll
    for (int u = 0; u < NU; ++u) acc[u] += v * bfpair(g[u]);
}

// MODE 0: write bf16. MODE 2: (C==128) add bias, L2-normalize row, write fp32.
template<int C, int MODE>
__global__ __launch_bounds__(256, 8) void spmm_gather(
    const short* __restrict__ H, const int* __restrict__ row_start,
    const int2* __restrict__ epk, void* __restrict__ outv,
    const float* __restrict__ bias, int N)
{
    constexpr int NU = C / 64;
    const int wid = threadIdx.x >> 6;
    const int lane = threadIdx.x & 63;
    const bool hi = lane >= 32;
    const int l31 = lane & 31;
    const int loff = l31 * NU;
    const int row = blockIdx.x * 4 + wid;
    if (row >= N) return;
    int j = row_start[row];
    const int end = row_start[row + 1];
    const unsigned* Hb = (const unsigned*)H;

    f32x2 acc[NU];
    #pragma unroll
    for (int u = 0; u < NU; ++u) acc[u] = f32x2{0.f, 0.f};

    for (; j + 16 <= end; j += 16) pair_batch<8, NU>(Hb, epk, j, hi, loff, acc);
    if (j + 8 <= end) { pair_batch<4, NU>(Hb, epk, j, hi, loff, acc); j += 8; }
    if (j + 4 <= end) { pair_batch<2, NU>(Hb, epk, j, hi, loff, acc); j += 4; }
    if (j + 2 <= end) { pair_batch<1, NU>(Hb, epk, j, hi, loff, acc); j += 2; }
    if (j < end)      edge_tail<NU>(Hb, epk, j, hi, loff, acc);

    // fold the two half-wave partial sums (even edges | odd edges)
    #pragma unroll
    for (int u = 0; u < NU; ++u) {
        acc[u].x += __shfl_xor(acc[u].x, 32);
        acc[u].y += __shfl_xor(acc[u].y, 32);
    }

    if constexpr (MODE == 0) {
        if (lane < 32) {
            unsigned od[NU];
            #pragma unroll
            for (int u = 0; u < NU; ++u)
                od[u] = (unsigned)(unsigned short)f2bf(acc[u].x)
                      | ((unsigned)(unsigned short)f2bf(acc[u].y) << 16);
            unsigned* orow = (unsigned*)outv + (size_t)row * (32 * NU) + loff;
            if constexpr (NU == 4) *(uint4*)orow = uint4{od[0], od[1], od[2], od[3]};
            else                   *(uint2*)orow = uint2{od[0], od[1]};
        }
    } else {
        const int c0 = l31 * 4;   // C==128: 4 channels per lane (in each half)
        float o0 = acc[0].x + bias[c0];
        float o1 = acc[0].y + bias[c0 + 1];
        float o2 = acc[1].x + bias[c0 + 2];
        float o3 = acc[1].y + bias[c0 + 3];
        float ss = o0 * o0 + o1 * o1 + o2 * o2 + o3 * o3;
        #pragma unroll
        for (int d = 1; d < 32; d <<= 1)
            ss += __shfl_xor(ss, d);
        float s = 1.0f / fmaxf(sqrtf(ss), 1e-12f);
        if (lane < 32)
            *(float4*)((float*)outv + (size_t)row * C + c0) =
                float4{o0 * s, o1 * s, o2 * s, o3 * s};
    }
}

// ================= bf16 MFMA GEMM, 128x64 tile, XCD-aware swizzle =================
template<int K, int M, bool RELU, bool BIAS>
__global__ __launch_bounds__(256) void gemm_bf16(
    const short* __restrict__ A, const short* __restrict__ W,
    const float* __restrict__ bias, short* __restrict__ Y, int N)
{
    constexpr int MBLK = M / 64;
    constexpr int BK = 32;
    constexpr int PAD = 8;
    __shared__ short As[128][BK + PAD];
    __shared__ short Ws[64][BK + PAD];

    const int id = blockIdx.x;
    const int bx = (id / (8 * MBLK)) * 8 + (id & 7);
    const int by = (id >> 3) & (MBLK - 1);

    const int tid = threadIdx.x;
    const int wid = tid >> 6;
    const int lane = tid & 63;
    const int wm = wid & 1;
    const int wn = wid >> 1;
    const int l15 = lane & 15;
    const int quad = lane >> 4;
    const int bn = bx * 128;
    const int bm = by * 64;

    f32x4 acc[4][2] = {};

    for (int k0 = 0; k0 < K; k0 += BK) {
        #pragma unroll
        for (int c = 0; c < 2; ++c) {
            int chunk = tid + c * 256;
            int row = chunk >> 2;
            int koff = (chunk & 3) * 8;
            int gr = bn + row;
            ulonglong2 v = {0ull, 0ull};
            if (gr < N) v = *(const ulonglong2*)(A + (size_t)gr * K + k0 + koff);
            *(ulonglong2*)&As[row][koff] = v;
        }
        {
            int row = tid >> 2;
            int koff = (tid & 3) * 8;
            ulonglong2 v = *(const ulonglong2*)(W + (size_t)(bm + row) * K + k0 + koff);
            *(ulonglong2*)&Ws[row][koff] = v;
        }
        __syncthreads();

        bf16x8 aF[4], bF[2];
        #pragma unroll
        for (int mt = 0; mt < 4; ++mt)
            aF[mt] = *(const bf16x8*)&As[wm * 64 + mt * 16 + l15][quad * 8];
        #pragma unroll
        for (int nt = 0; nt < 2; ++nt)
            bF[nt] = *(const bf16x8*)&Ws[wn * 32 + nt * 16 + l15][quad * 8];

        #pragma unroll
        for (int mt = 0; mt < 4; ++mt)
            #pragma unroll
            for (int nt = 0; nt < 2; ++nt)
                acc[mt][nt] = __builtin_amdgcn_mfma_f32_16x16x32_bf16(
                    aF[mt], bF[nt], acc[mt][nt], 0, 0, 0);
        __syncthreads();
    }

    #pragma unroll
    for (int nt = 0; nt < 2; ++nt) {
        int col = bm + wn * 32 + nt * 16 + l15;
        float bv = BIAS ? bias[col] : 0.f;
        #pragma unroll
        for (int mt = 0; mt < 4; ++mt) {
            int row0 = bn + wm * 64 + mt * 16 + quad * 4;
            #pragma unroll
            for (int r = 0; r < 4; ++r) {
                int row = row0 + r;
                if (row < N) {
                    float v = acc[mt][nt][r] + bv;
                    if (RELU) v = fmaxf(v, 0.f);
                    Y[(size_t)row * M + col] = f2bf(v);
                }
            }
        }
    }
}

// ================= fused dense GEMM2+GEMM3 (no gather inside) =================
// Per block: 64 rows. Phase A: coalesced load of the [64 x CIN] A-tile to LDS.
// Phase B: tile @ W2^T (+bias2, relu) -> restage bf16 in the same LDS tile.
// Phase C: tile @ W3^T -> write bf16. Saves the G2 round-trip (102 MB) and a
// dispatch; numerics identical (same f2bf rounding point as the unfused chain).
template<int CIN, int COUT, int C3>
__global__ __launch_bounds__(256, 4) void gemm23(
    const short* __restrict__ A,
    const short* __restrict__ W2, const float* __restrict__ bias2,
    const short* __restrict__ W3,
    short* __restrict__ Y3, int N)
{
    constexpr int LDW = CIN + 8;
    __shared__ short As[64][LDW];

    const int tid = threadIdx.x;
    const int wid = tid >> 6;
    const int lane = tid & 63;
    const int rb = blockIdx.x * 64;

    // phase A: dense coalesced tile load
    #pragma unroll
    for (int c = 0; c < (64 * CIN) / (8 * 256); ++c) {
        int chunk = tid + c * 256;
        int row = chunk / (CIN / 8);
        int koff = (chunk % (CIN / 8)) * 8;
        int gr = rb + row;
        ulonglong2 v = {0ull, 0ull};
        if (gr < N) v = *(const ulonglong2*)(A + (size_t)gr * CIN + koff);
        *(ulonglong2*)&As[row][koff] = v;
    }
    __syncthreads();

    const int wm = wid & 1;
    const int wn = wid >> 1;
    const int l15 = lane & 15;
    const int quad = lane >> 4;

    // phase B: [64 x CIN] @ W2[COUT x CIN]^T
    constexpr int NT = COUT / 32;
    f32x4 acc[2][NT] = {};
    for (int k0 = 0; k0 < CIN; k0 += 32) {
        bf16x8 aF[2];
        #pragma unroll
        for (int mt = 0; mt < 2; ++mt)
            aF[mt] = *(const bf16x8*)&As[wm * 32 + mt * 16 + l15][k0 + quad * 8];
        #pragma unroll
        for (int nc = 0; nc < NT; nc += 4) {
            bf16x8 bF[4];
            #pragma unroll
            for (int i = 0; i < 4; ++i) {
                const int col = wn * (COUT / 2) + (nc + i) * 16 + l15;
                bF[i] = *(const bf16x8*)&W2[(size_t)col * CIN + k0 + quad * 8];
            }
            #pragma unroll
            for (int mt = 0; mt < 2; ++mt)
                #pragma unroll
                for (int i = 0; i < 4; ++i)
                    acc[mt][nc + i] = __builtin_amdgcn_mfma_f32_16x16x32_bf16(
                        aF[mt], bF[i], acc[mt][nc + i], 0, 0, 0);
        }
    }

    __syncthreads();   // all waves done reading As
    // restage relu(acc + bias2) as bf16: C/D frag layout col=lane&15, row=(lane>>4)*4+r
    #pragma unroll
    for (int nt = 0; nt < NT; ++nt) {
        const int col = wn * (COUT / 2) + nt * 16 + l15;
        const float bv = bias2[col];
        #pragma unroll
        for (int mt = 0; mt < 2; ++mt) {
            const int lr0 = wm * 32 + mt * 16 + quad * 4;
            #pragma unroll
            for (int r = 0; r < 4; ++r)
                As[lr0 + r][col] = f2bf(fmaxf(acc[mt][nt][r] + bv, 0.f));
        }
    }
    __syncthreads();

    // phase C: [64 x COUT] @ W3[C3 x COUT]^T
    constexpr int NT3 = C3 / 32;
    f32x4 acc3[2][NT3] = {};
    for (int k0 = 0; k0 < COUT; k0 += 32) {
        bf16x8 aF[2];
        #pragma unroll
        for (int mt = 0; mt < 2; ++mt)
            aF[mt] = *(const bf16x8*)&As[wm * 32 + mt * 16 + l15][k0 + quad * 8];
        bf16x8 bF[NT3];
        #pragma unroll
        for (int nt = 0; nt < NT3; ++nt) {
            const int col = wn * (C3 / 2) + nt * 16 + l15;
            bF[nt] = *(const bf16x8*)&W3[(size_t)col * COUT + k0 + quad * 8];
        }
        #pragma unroll
        for (int mt = 0; mt < 2; ++mt)
            #pragma unroll
            for (int nt = 0; nt < NT3; ++nt)
                acc3[mt][nt] = __builtin_amdgcn_mfma_f32_16x16x32_bf16(
                    aF[mt], bF[nt], acc3[mt][nt], 0, 0, 0);
    }
    #pragma unroll
    for (int nt = 0; nt < NT3; ++nt) {
        const int col = wn * (C3 / 2) + nt * 16 + l15;
        #pragma unroll
        for (int mt = 0; mt < 2; ++mt) {
            const int row0 = rb + wm * 32 + mt * 16 + quad * 4;
            #pragma unroll
            for (int r = 0; r < 4; ++r) {
                const int row = row0 + r;
                if (row < N)
                    Y3[(size_t)row * C3 + col] = f2bf(acc3[mt][nt][r]);
            }
        }
    }
}

extern "C" void kernel_launch(void* const* d_in, const int* in_sizes, int n_in,
                              void* d_out, int out_size, void* d_ws, size_t ws_size,
                              hipStream_t stream) {
    const float* x        = (const float*)d_in[0];
    const int*   edge_row = (const int*)d_in[1];
    const int*   edge_col = (const int*)d_in[2];
    const float* edge_val = (const float*)d_in[3];
    const float* W1       = (const float*)d_in[4];
    const float* b1       = (const float*)d_in[5];
    const float* W2       = (const float*)d_in[6];
    const float* b2       = (const float*)d_in[7];
    const float* W3       = (const float*)d_in[8];
    const float* b3       = (const float*)d_in[9];
    float* out = (float*)d_out;

    const int N = N_NODES, E = N_EDGES;
    const int NB = (N + SCAN_ELEMS - 1) / SCAN_ELEMS;   // 98

    // workspace layout
    short* xbf = (short*)d_ws;                    // [N,128] bf16 x; later H3
    short* Hbf = xbf + (size_t)N * IN_C;          // [N,256] bf16 (spmm outputs)
    short* Gbf = Hbf + (size_t)N * HID_C;         // [N,256] bf16 G1
    short* W1b = Gbf + (size_t)N * HID_C;         // [256,128]
    short* W2b = W1b + HID_C * IN_C;              // [256,256]
    short* W3b = W2b + HID_C * HID_C;             // [128,256]
    int* deg = (int*)(((uintptr_t)(W3b + OUT_C * HID_C) + 15) & ~(uintptr_t)15);
    int* row_start = deg + N;                     // [N+1]
    int* rank      = row_start + (N + 1);         // [E]
    int* bsum      = rank + E;                    // [128]
    int2* epk      = (int2*)(((uintptr_t)(bsum + 128) + 15) & ~(uintptr_t)15);  // [E]

    // ---- build CSR (atomic-free scatter) + casts ----
    hipMemsetAsync(deg, 0, N * sizeof(int), stream);
    hist_rank<<<(E + 255) / 256, 256, 0, stream>>>(edge_row, deg, rank, E);
    scan1<<<NB, SCAN_BLOCK, 0, stream>>>(deg, row_start, bsum, N);
    scan3<<<(N + 256) / 256, 256, 0, stream>>>(row_start, bsum, NB, N, E);
    {
        int n0 = N * IN_C, n1 = HID_C * IN_C, n2 = HID_C * HID_C, n3 = OUT_C * HID_C;
        int total = E + (n0 + n1 + n2 + n3) / 4;   // both parts wave-aligned
        scatter_cast<<<(total + 255) / 256, 256, 0, stream>>>(
            edge_row, edge_col, edge_val, row_start, rank, epk, E,
            x, xbf, n0, W1, W1b, n1, W2, W2b, n2, W3, W3b, n3);
    }

    const int spmm_grid = (N + 3) / 4;
    const int GXP = ((N + 127) / 128 + 7) & ~7;   // padded strips (OOB guarded)
    const int fgrid = (N + 63) / 64;              // 1563

    // Layer 1: Hbf = spmm(xbf) [N,128]; Gbf = relu(Hbf@W1.T+b1) [N,256]
    spmm_gather<IN_C, 0><<<spmm_grid, 256, 0, stream>>>(
        xbf, row_start, epk, Hbf, nullptr, N);
    gemm_bf16<IN_C, HID_C, true, true><<<GXP * (HID_C / 64), 256, 0, stream>>>(
        Hbf, W1b, b1, Gbf, N);

    // Layer 2 spmm: Hbf = spmm(Gbf) [N,256]
    spmm_gather<HID_C, 0><<<spmm_grid, 256, 0, stream>>>(
        Gbf, row_start, epk, Hbf, nullptr, N);

    // Layers 2+3 dense fused: H3 = relu(Hbf@W2.T+b2) @ W3.T  -> xbf
    gemm23<HID_C, HID_C, OUT_C><<<fgrid, 256, 0, stream>>>(
        Hbf, W2b, b2, W3b, xbf, N);

    // Final: out = normalize(spmm(H3) + b3)
    spmm_gather<OUT_C, 2><<<spmm_grid, 256, 0, stream>>>(
        xbf, row_start, epk, out, b3, N);
}

// Round 4
// 589.726 us; speedup vs baseline: 1.3093x; 1.3093x over previous
//
#include <hip/hip_runtime.h>
#include <hip/hip_bf16.h>

#define N_NODES 100000
#define N_EDGES 1600000
#define IN_C 128
#define HID_C 256
#define OUT_C 128

typedef __attribute__((ext_vector_type(8))) short bf16x8;
typedef __attribute__((ext_vector_type(4))) float f32x4;
typedef __attribute__((ext_vector_type(2))) float f32x2;

static __device__ __forceinline__ short f2bf(float f) {
    union { float f; unsigned u; } x{f};
    unsigned r = (x.u + 0x7fffu + ((x.u >> 16) & 1u)) >> 16;
    return (short)r;
}
static __device__ __forceinline__ f32x2 bfpair(unsigned d) {
    union { unsigned u; float f; } lo, hi;
    lo.u = d << 16;
    hi.u = d & 0xffff0000u;
    return f32x2{lo.f, hi.f};
}

// ================= CSR build =================
__global__ void hist_rank(const int* __restrict__ rows, int* __restrict__ deg,
                          int* __restrict__ rank, int E)
{
    int e = blockIdx.x * blockDim.x + threadIdx.x;
    if (e < E) rank[e] = atomicAdd(&deg[rows[e]], 1);
}

#define SCAN_BLOCK 256
#define SCAN_ELEMS 1024

__global__ __launch_bounds__(SCAN_BLOCK) void scan1(const int* __restrict__ deg,
                                                    int* __restrict__ excl,
                                                    int* __restrict__ bsum, int N)
{
    __shared__ int sh[SCAN_BLOCK];
    int t = threadIdx.x;
    int base = blockIdx.x * SCAN_ELEMS + t * 4;
    int v[4];
    #pragma unroll
    for (int i = 0; i < 4; ++i) {
        int idx = base + i;
        v[i] = (idx < N) ? deg[idx] : 0;
    }
    int s = v[0] + v[1] + v[2] + v[3];
    sh[t] = s;
    __syncthreads();
    for (int d = 1; d < SCAN_BLOCK; d <<= 1) {
        int add = (t >= d) ? sh[t - d] : 0;
        __syncthreads();
        sh[t] += add;
        __syncthreads();
    }
    int p = sh[t] - s;
    #pragma unroll
    for (int i = 0; i < 4; ++i) {
        int idx = base + i;
        if (idx < N) excl[idx] = p;
        p += v[i];
    }
    if (t == SCAN_BLOCK - 1) bsum[blockIdx.x] = sh[t];
}

// scan2 folded in: every block recomputes the (<=128-entry) block-sum prefix in LDS.
__global__ void scan3(int* __restrict__ row_start, const int* __restrict__ bsum,
                      int NB, int N, int E)
{
    __shared__ int pref[128];
    int t = threadIdx.x;
    if (t < 128) pref[t] = (t < NB) ? bsum[t] : 0;
    __syncthreads();
    for (int d = 1; d < 128; d <<= 1) {
        int add = (t < 128 && t >= d) ? pref[t - d] : 0;
        __syncthreads();
        if (t < 128) pref[t] += add;
        __syncthreads();
    }
    int i = blockIdx.x * blockDim.x + t;
    if (i < N) {
        int b = i >> 10;
        row_start[i] += (b == 0) ? 0 : pref[b - 1];
    } else if (i == N) {
        row_start[N] = E;
    }
}

// atomic-free scatter fused with bf16 casts (wave-aligned seam: E % 64 == 0)
__global__ void scatter_cast(const int* __restrict__ rows, const int* __restrict__ cols,
                             const float* __restrict__ vals, const int* __restrict__ row_start,
                             const int* __restrict__ rank, int2* __restrict__ epk, int E,
                             const float* __restrict__ s0, short* __restrict__ d0, int n0,
                             const float* __restrict__ s1, short* __restrict__ d1, int n1,
                             const float* __restrict__ s2, short* __restrict__ d2, int n2,
                             const float* __restrict__ s3, short* __restrict__ d3, int n3)
{
    int idx = blockIdx.x * blockDim.x + threadIdx.x;
    if (idx < E) {
        int pos = row_start[rows[idx]] + rank[idx];
        epk[pos] = int2{cols[idx], __float_as_int(vals[idx])};
    } else {
        int i = (idx - E) * 4;
        int castN = n0 + n1 + n2 + n3;
        if (i >= castN) return;
        const float* s; short* d;
        if (i < n0) { s = s0; d = d0; }
        else if ((i -= n0) < n1) { s = s1; d = d1; }
        else if ((i -= n1) < n2) { s = s2; d = d2; }
        else { i -= n2; s = s3; d = d3; }
        float4 v = *(const float4*)(s + i);
        *(short4*)(d + i) = short4{f2bf(v.x), f2bf(v.y), f2bf(v.z), f2bf(v.w)};
    }
}

// ================= unpaired gather SpMM (round-0 form; used for C=256) =========
template<int B, int ND>
static __device__ __forceinline__ void spmm_batch(
    const unsigned* __restrict__ Hb, const int2* __restrict__ epk,
    int j, int loff, f32x2* acc)
{
    int2 e[B];
    #pragma unroll
    for (int b = 0; b < B; ++b) e[b] = epk[j + b];
    uint2 g[B];
    #pragma unroll
    for (int b = 0; b < B; ++b) {
        const unsigned* p = Hb + (size_t)e[b].x * (64 * ND) + loff;
        if constexpr (ND == 2) g[b] = *(const uint2*)p;
        else                   g[b].x = *p;
    }
    #pragma unroll
    for (int b = 0; b < B; ++b) {
        float v = __int_as_float(e[b].y);
        acc[0] += v * bfpair(g[b].x);
        if constexpr (ND == 2) acc[1] += v * bfpair(g[b].y);
    }
}

// C=256, MODE 0 only: one edge per wave-wide load (64 lanes x uint2 = full row).
template<int C>
__global__ __launch_bounds__(256) void spmm_gather_u(
    const short* __restrict__ H, const int* __restrict__ row_start,
    const int2* __restrict__ epk, void* __restrict__ outv, int N)
{
    constexpr int ND = C / 128;
    int wid = threadIdx.x >> 6;
    int lane = threadIdx.x & 63;
    int row = blockIdx.x * 4 + wid;
    if (row >= N) return;
    int j = row_start[row];
    int end = row_start[row + 1];
    const unsigned* Hb = (const unsigned*)H;
    const int loff = lane * ND;

    f32x2 acc[ND];
    #pragma unroll
    for (int d = 0; d < ND; ++d) acc[d] = f32x2{0.f, 0.f};

    for (; j + 8 <= end; j += 8) spmm_batch<8, ND>(Hb, epk, j, loff, acc);
    if (j + 4 <= end) { spmm_batch<4, ND>(Hb, epk, j, loff, acc); j += 4; }
    if (j + 2 <= end) { spmm_batch<2, ND>(Hb, epk, j, loff, acc); j += 2; }
    if (j < end)      { spmm_batch<1, ND>(Hb, epk, j, loff, acc); }

    unsigned od[ND];
    #pragma unroll
    for (int d = 0; d < ND; ++d)
        od[d] = (unsigned)(unsigned short)f2bf(acc[d].x)
              | ((unsigned)(unsigned short)f2bf(acc[d].y) << 16);
    unsigned* orow = (unsigned*)outv + (size_t)row * (64 * ND) + loff;
    if constexpr (ND == 2) *(uint2*)orow = uint2{od[0], od[1]};
    else                   *orow = od[0];
}

// ================= paired gather SpMM (C=128 only) =================
// 2 edges per wave-wide load: lanes 0-31 own edge j+2b, lanes 32-63 own edge
// j+2b+1 (per-lane epk select -- each lane holds ONE edge descriptor, so the
// live set matches the unpaired kernel; no cndmask, no dual arrays -> no spill).
// Both halves cover the same 64 channels; one shfl_xor(32) fold per row end.
// Halves wave-load count at equal bytes (gather measured request-bound).
template<int B>
static __device__ __forceinline__ void pair_batch(
    const unsigned* __restrict__ Hb, const int2* __restrict__ epk,
    int j, int sel, int loff, f32x2* acc)
{
    int2 e[B];
    #pragma unroll
    for (int b = 0; b < B; ++b) e[b] = epk[j + 2 * b + sel];
    uint2 g[B];
    #pragma unroll
    for (int b = 0; b < B; ++b)
        g[b] = *(const uint2*)(Hb + (size_t)e[b].x * 64 + loff);
    #pragma unroll
    for (int b = 0; b < B; ++b) {
        const float v = __int_as_float(e[b].y);
        acc[0] += v * bfpair(g[b].x);
        acc[1] += v * bfpair(g[b].y);
    }
}

// MODE 0: write bf16 row. MODE 2: add bias, L2-normalize, write fp32 row.
template<int MODE>
__global__ __launch_bounds__(256) void spmm_gather_p(
    const short* __restrict__ H, const int* __restrict__ row_start,
    const int2* __restrict__ epk, void* __restrict__ outv,
    const float* __restrict__ bias, int N)
{
    const int wid = threadIdx.x >> 6;
    const int lane = threadIdx.x & 63;
    const int sel = lane >> 5;        // 0: even edges, 1: odd edges
    const int l31 = lane & 31;
    const int loff = l31 * 2;         // uint2 per lane over 32 lanes = 64 unsigneds
    const int row = blockIdx.x * 4 + wid;
    if (row >= N) return;
    int j = row_start[row];
    const int end = row_start[row + 1];
    const unsigned* Hb = (const unsigned*)H;

    f32x2 acc[2] = {f32x2{0.f, 0.f}, f32x2{0.f, 0.f}};

    for (; j + 16 <= end; j += 16) pair_batch<8>(Hb, epk, j, sel, loff, acc);
    if (j + 8 <= end) { pair_batch<4>(Hb, epk, j, sel, loff, acc); j += 8; }
    if (j + 4 <= end) { pair_batch<2>(Hb, epk, j, sel, loff, acc); j += 4; }
    if (j + 2 <= end) { pair_batch<1>(Hb, epk, j, sel, loff, acc); j += 2; }
    if (j < end) {
        // single leftover edge: both halves load it; hi half contributes 0
        int2 e = epk[j];
        uint2 g = *(const uint2*)(Hb + (size_t)e.x * 64 + loff);
        const float v = sel ? 0.f : __int_as_float(e.y);
        acc[0] += v * bfpair(g.x);
        acc[1] += v * bfpair(g.y);
    }

    // fold even-edge and odd-edge partial sums
    #pragma unroll
    for (int u = 0; u < 2; ++u) {
        acc[u].x += __shfl_xor(acc[u].x, 32);
        acc[u].y += __shfl_xor(acc[u].y, 32);
    }

    if constexpr (MODE == 0) {
        if (lane < 32) {
            unsigned o0 = (unsigned)(unsigned short)f2bf(acc[0].x)
                        | ((unsigned)(unsigned short)f2bf(acc[0].y) << 16);
            unsigned o1 = (unsigned)(unsigned short)f2bf(acc[1].x)
                        | ((unsigned)(unsigned short)f2bf(acc[1].y) << 16);
            *(uint2*)((unsigned*)outv + (size_t)row * 64 + loff) = uint2{o0, o1};
        }
    } else {
        const int c0 = l31 * 4;       // 4 channels per lane within each half
        float o0 = acc[0].x + bias[c0];
        float o1 = acc[0].y + bias[c0 + 1];
        float o2 = acc[1].x + bias[c0 + 2];
        float o3 = acc[1].y + bias[c0 + 3];
        float ss = o0 * o0 + o1 * o1 + o2 * o2 + o3 * o3;
        #pragma unroll
        for (int d = 1; d < 32; d <<= 1)
            ss += __shfl_xor(ss, d);
        float s = 1.0f / fmaxf(sqrtf(ss), 1e-12f);
        if (lane < 32)
            *(float4*)((float*)outv + (size_t)row * 128 + c0) =
                float4{o0 * s, o1 * s, o2 * s, o3 * s};
    }
}

// ================= bf16 MFMA GEMM, 128x64 tile, XCD-aware swizzle =================
template<int K, int M, bool RELU, bool BIAS>
__global__ __launch_bounds__(256) void gemm_bf16(
    const short* __restrict__ A, const short* __restrict__ W,
    const float* __restrict__ bias, short* __restrict__ Y, int N)
{
    constexpr int MBLK = M / 64;
    constexpr int BK = 32;
    constexpr int PAD = 8;
    __shared__ short As[128][BK + PAD];
    __shared__ short Ws[64][BK + PAD];

    const int id = blockIdx.x;
    const int bx = (id / (8 * MBLK)) * 8 + (id & 7);
    const int by = (id >> 3) & (MBLK - 1);

    const int tid = threadIdx.x;
    const int wid = tid >> 6;
    const int lane = tid & 63;
    const int wm = wid & 1;
    const int wn = wid >> 1;
    const int l15 = lane & 15;
    const int quad = lane >> 4;
    const int bn = bx * 128;
    const int bm = by * 64;

    f32x4 acc[4][2] = {};

    for (int k0 = 0; k0 < K; k0 += BK) {
        #pragma unroll
        for (int c = 0; c < 2; ++c) {
            int chunk = tid + c * 256;
            int row = chunk >> 2;
            int koff = (chunk & 3) * 8;
            int gr = bn + row;
            ulonglong2 v = {0ull, 0ull};
            if (gr < N) v = *(const ulonglong2*)(A + (size_t)gr * K + k0 + koff);
            *(ulonglong2*)&As[row][koff] = v;
        }
        {
            int row = tid >> 2;
            int koff = (tid & 3) * 8;
            ulonglong2 v = *(const ulonglong2*)(W + (size_t)(bm + row) * K + k0 + koff);
            *(ulonglong2*)&Ws[row][koff] = v;
        }
        __syncthreads();

        bf16x8 aF[4], bF[2];
        #pragma unroll
        for (int mt = 0; mt < 4; ++mt)
            aF[mt] = *(const bf16x8*)&As[wm * 64 + mt * 16 + l15][quad * 8];
        #pragma unroll
        for (int nt = 0; nt < 2; ++nt)
            bF[nt] = *(const bf16x8*)&Ws[wn * 32 + nt * 16 + l15][quad * 8];

        #pragma unroll
        for (int mt = 0; mt < 4; ++mt)
            #pragma unroll
            for (int nt = 0; nt < 2; ++nt)
                acc[mt][nt] = __builtin_amdgcn_mfma_f32_16x16x32_bf16(
                    aF[mt], bF[nt], acc[mt][nt], 0, 0, 0);
        __syncthreads();
    }

    #pragma unroll
    for (int nt = 0; nt < 2; ++nt) {
        int col = bm + wn * 32 + nt * 16 + l15;
        float bv = BIAS ? bias[col] : 0.f;
        #pragma unroll
        for (int mt = 0; mt < 4; ++mt) {
            int row0 = bn + wm * 64 + mt * 16 + quad * 4;
            #pragma unroll
            for (int r = 0; r < 4; ++r) {
                int row = row0 + r;
                if (row < N) {
                    float v = acc[mt][nt][r] + bv;
                    if (RELU) v = fmaxf(v, 0.f);
                    Y[(size_t)row * M + col] = f2bf(v);
                }
            }
        }
    }
}

// ================= fused dense GEMM2+GEMM3 (no gather inside) =================
template<int CIN, int COUT, int C3>
__global__ __launch_bounds__(256, 4) void gemm23(
    const short* __restrict__ A,
    const short* __restrict__ W2, const float* __restrict__ bias2,
    const short* __restrict__ W3,
    short* __restrict__ Y3, int N)
{
    constexpr int LDW = CIN + 8;
    __shared__ short As[64][LDW];

    const int tid = threadIdx.x;
    const int wid = tid >> 6;
    const int lane = tid & 63;
    const int rb = blockIdx.x * 64;

    // phase A: dense coalesced tile load
    #pragma unroll
    for (int c = 0; c < (64 * CIN) / (8 * 256); ++c) {
        int chunk = tid + c * 256;
        int row = chunk / (CIN / 8);
        int koff = (chunk % (CIN / 8)) * 8;
        int gr = rb + row;
        ulonglong2 v = {0ull, 0ull};
        if (gr < N) v = *(const ulonglong2*)(A + (size_t)gr * CIN + koff);
        *(ulonglong2*)&As[row][koff] = v;
    }
    __syncthreads();

    const int wm = wid & 1;
    const int wn = wid >> 1;
    const int l15 = lane & 15;
    const int quad = lane >> 4;

    // phase B: [64 x CIN] @ W2[COUT x CIN]^T
    constexpr int NT = COUT / 32;
    f32x4 acc[2][NT] = {};
    for (int k0 = 0; k0 < CIN; k0 += 32) {
        bf16x8 aF[2];
        #pragma unroll
        for (int mt = 0; mt < 2; ++mt)
            aF[mt] = *(const bf16x8*)&As[wm * 32 + mt * 16 + l15][k0 + quad * 8];
        #pragma unroll
        for (int nc = 0; nc < NT; nc += 4) {
            bf16x8 bF[4];
            #pragma unroll
            for (int i = 0; i < 4; ++i) {
                const int col = wn * (COUT / 2) + (nc + i) * 16 + l15;
                bF[i] = *(const bf16x8*)&W2[(size_t)col * CIN + k0 + quad * 8];
            }
            #pragma unroll
            for (int mt = 0; mt < 2; ++mt)
                #pragma unroll
                for (int i = 0; i < 4; ++i)
                    acc[mt][nc + i] = __builtin_amdgcn_mfma_f32_16x16x32_bf16(
                        aF[mt], bF[i], acc[mt][nc + i], 0, 0, 0);
        }
    }

    __syncthreads();   // all waves done reading As
    // restage relu(acc + bias2) as bf16: C/D frag layout col=lane&15, row=(lane>>4)*4+r
    #pragma unroll
    for (int nt = 0; nt < NT; ++nt) {
        const int col = wn * (COUT / 2) + nt * 16 + l15;
        const float bv = bias2[col];
        #pragma unroll
        for (int mt = 0; mt < 2; ++mt) {
            const int lr0 = wm * 32 + mt * 16 + quad * 4;
            #pragma unroll
            for (int r = 0; r < 4; ++r)
                As[lr0 + r][col] = f2bf(fmaxf(acc[mt][nt][r] + bv, 0.f));
        }
    }
    __syncthreads();

    // phase C: [64 x COUT] @ W3[C3 x COUT]^T
    constexpr int NT3 = C3 / 32;
    f32x4 acc3[2][NT3] = {};
    for (int k0 = 0; k0 < COUT; k0 += 32) {
        bf16x8 aF[2];
        #pragma unroll
        for (int mt = 0; mt < 2; ++mt)
            aF[mt] = *(const bf16x8*)&As[wm * 32 + mt * 16 + l15][k0 + quad * 8];
        bf16x8 bF[NT3];
        #pragma unroll
        for (int nt = 0; nt < NT3; ++nt) {
            const int col = wn * (C3 / 2) + nt * 16 + l15;
            bF[nt] = *(const bf16x8*)&W3[(size_t)col * COUT + k0 + quad * 8];
        }
        #pragma unroll
        for (int mt = 0; mt < 2; ++mt)
            #pragma unroll
            for (int nt = 0; nt < NT3; ++nt)
                acc3[mt][nt] = __builtin_amdgcn_mfma_f32_16x16x32_bf16(
                    aF[mt], bF[nt], acc3[mt][nt], 0, 0, 0);
    }
    #pragma unroll
    for (int nt = 0; nt < NT3; ++nt) {
        const int col = wn * (C3 / 2) + nt * 16 + l15;
        #pragma unroll
        for (int mt = 0; mt < 2; ++mt) {
            const int row0 = rb + wm * 32 + mt * 16 + quad * 4;
            #pragma unroll
            for (int r = 0; r < 4; ++r) {
                const int row = row0 + r;
                if (row < N)
                    Y3[(size_t)row * C3 + col] = f2bf(acc3[mt][nt][r]);
            }
        }
    }
}

extern "C" void kernel_launch(void* const* d_in, const int* in_sizes, int n_in,
                              void* d_out, int out_size, void* d_ws, size_t ws_size,
                              hipStream_t stream) {
    const float* x        = (const float*)d_in[0];
    const int*   edge_row = (const int*)d_in[1];
    const int*   edge_col = (const int*)d_in[2];
    const float* edge_val = (const float*)d_in[3];
    const float* W1       = (const float*)d_in[4];
    const float* b1       = (const float*)d_in[5];
    const float* W2       = (const float*)d_in[6];
    const float* b2       = (const float*)d_in[7];
    const float* W3       = (const float*)d_in[8];
    const float* b3       = (const float*)d_in[9];
    float* out = (float*)d_out;

    const int N = N_NODES, E = N_EDGES;
    const int NB = (N + SCAN_ELEMS - 1) / SCAN_ELEMS;   // 98

    // workspace layout
    short* xbf = (short*)d_ws;                    // [N,128] bf16 x; later H3
    short* Hbf = xbf + (size_t)N * IN_C;          // [N,256] bf16 (spmm outputs)
    short* Gbf = Hbf + (size_t)N * HID_C;         // [N,256] bf16 G1
    short* W1b = Gbf + (size_t)N * HID_C;         // [256,128]
    short* W2b = W1b + HID_C * IN_C;              // [256,256]
    short* W3b = W2b + HID_C * HID_C;             // [128,256]
    int* deg = (int*)(((uintptr_t)(W3b + OUT_C * HID_C) + 15) & ~(uintptr_t)15);
    int* row_start = deg + N;                     // [N+1]
    int* rank      = row_start + (N + 1);         // [E]
    int* bsum      = rank + E;                    // [128]
    int2* epk      = (int2*)(((uintptr_t)(bsum + 128) + 15) & ~(uintptr_t)15);  // [E]

    // ---- build CSR (atomic-free scatter) + casts ----
    hipMemsetAsync(deg, 0, N * sizeof(int), stream);
    hist_rank<<<(E + 255) / 256, 256, 0, stream>>>(edge_row, deg, rank, E);
    scan1<<<NB, SCAN_BLOCK, 0, stream>>>(deg, row_start, bsum, N);
    scan3<<<(N + 256) / 256, 256, 0, stream>>>(row_start, bsum, NB, N, E);
    {
        int n0 = N * IN_C, n1 = HID_C * IN_C, n2 = HID_C * HID_C, n3 = OUT_C * HID_C;
        int total = E + (n0 + n1 + n2 + n3) / 4;   // both parts wave-aligned
        scatter_cast<<<(total + 255) / 256, 256, 0, stream>>>(
            edge_row, edge_col, edge_val, row_start, rank, epk, E,
            x, xbf, n0, W1, W1b, n1, W2, W2b, n2, W3, W3b, n3);
    }

    const int spmm_grid = (N + 3) / 4;
    const int GXP = ((N + 127) / 128 + 7) & ~7;   // padded strips (OOB guarded)
    const int fgrid = (N + 63) / 64;              // 1563

    // Layer 1: Hbf = spmm(xbf) [N,128] (paired); Gbf = relu(Hbf@W1.T+b1) [N,256]
    spmm_gather_p<0><<<spmm_grid, 256, 0, stream>>>(
        xbf, row_start, epk, Hbf, nullptr, N);
    gemm_bf16<IN_C, HID_C, true, true><<<GXP * (HID_C / 64), 256, 0, stream>>>(
        Hbf, W1b, b1, Gbf, N);

    // Layer 2 spmm (C=256, unpaired): Hbf = spmm(Gbf)
    spmm_gather_u<HID_C><<<spmm_grid, 256, 0, stream>>>(
        Gbf, row_start, epk, Hbf, N);

    // Layers 2+3 dense fused: H3 = relu(Hbf@W2.T+b2) @ W3.T  -> xbf
    gemm23<HID_C, HID_C, OUT_C><<<fgrid, 256, 0, stream>>>(
        Hbf, W2b, b2, W3b, xbf, N);

    // Final: out = normalize(spmm(H3) + b3)  (paired)
    spmm_gather_p<2><<<spmm_grid, 256, 0, stream>>>(
        xbf, row_start, epk, out, b3, N);
}

// Round 5
// 562.870 us; speedup vs baseline: 1.3717x; 1.0477x over previous
//
#include <hip/hip_runtime.h>
#include <hip/hip_bf16.h>

#define N_NODES 100000
#define N_EDGES 1600000
#define IN_C 128
#define HID_C 256
#define OUT_C 128

typedef __attribute__((ext_vector_type(8))) short bf16x8;
typedef __attribute__((ext_vector_type(4))) float f32x4;
typedef __attribute__((ext_vector_type(2))) float f32x2;

static __device__ __forceinline__ short f2bf(float f) {
    union { float f; unsigned u; } x{f};
    unsigned r = (x.u + 0x7fffu + ((x.u >> 16) & 1u)) >> 16;
    return (short)r;
}
static __device__ __forceinline__ f32x2 bfpair(unsigned d) {
    union { unsigned u; float f; } lo, hi;
    lo.u = d << 16;
    hi.u = d & 0xffff0000u;
    return f32x2{lo.f, hi.f};
}

// ================= CSR build =================
__global__ void hist_rank(const int* __restrict__ rows, int* __restrict__ deg,
                          int* __restrict__ rank, int E)
{
    int e = blockIdx.x * blockDim.x + threadIdx.x;
    if (e < E) rank[e] = atomicAdd(&deg[rows[e]], 1);
}

#define SCAN_BLOCK 256
#define SCAN_ELEMS 1024

__global__ __launch_bounds__(SCAN_BLOCK) void scan1(const int* __restrict__ deg,
                                                    int* __restrict__ excl,
                                                    int* __restrict__ bsum, int N)
{
    __shared__ int sh[SCAN_BLOCK];
    int t = threadIdx.x;
    int base = blockIdx.x * SCAN_ELEMS + t * 4;
    int v[4];
    #pragma unroll
    for (int i = 0; i < 4; ++i) {
        int idx = base + i;
        v[i] = (idx < N) ? deg[idx] : 0;
    }
    int s = v[0] + v[1] + v[2] + v[3];
    sh[t] = s;
    __syncthreads();
    for (int d = 1; d < SCAN_BLOCK; d <<= 1) {
        int add = (t >= d) ? sh[t - d] : 0;
        __syncthreads();
        sh[t] += add;
        __syncthreads();
    }
    int p = sh[t] - s;
    #pragma unroll
    for (int i = 0; i < 4; ++i) {
        int idx = base + i;
        if (idx < N) excl[idx] = p;
        p += v[i];
    }
    if (t == SCAN_BLOCK - 1) bsum[blockIdx.x] = sh[t];
}

// scan2 folded in: every block recomputes the (<=128-entry) block-sum prefix in LDS.
__global__ void scan3(int* __restrict__ row_start, const int* __restrict__ bsum,
                      int NB, int N, int E)
{
    __shared__ int pref[128];
    int t = threadIdx.x;
    if (t < 128) pref[t] = (t < NB) ? bsum[t] : 0;
    __syncthreads();
    for (int d = 1; d < 128; d <<= 1) {
        int add = (t < 128 && t >= d) ? pref[t - d] : 0;
        __syncthreads();
        if (t < 128) pref[t] += add;
        __syncthreads();
    }
    int i = blockIdx.x * blockDim.x + t;
    if (i < N) {
        int b = i >> 10;
        row_start[i] += (b == 0) ? 0 : pref[b - 1];
    } else if (i == N) {
        row_start[N] = E;
    }
}

// atomic-free scatter fused with bf16 casts (wave-aligned seam: E % 64 == 0)
__global__ void scatter_cast(const int* __restrict__ rows, const int* __restrict__ cols,
                             const float* __restrict__ vals, const int* __restrict__ row_start,
                             const int* __restrict__ rank, int2* __restrict__ epk, int E,
                             const float* __restrict__ s0, short* __restrict__ d0, int n0,
                             const float* __restrict__ s1, short* __restrict__ d1, int n1,
                             const float* __restrict__ s2, short* __restrict__ d2, int n2,
                             const float* __restrict__ s3, short* __restrict__ d3, int n3)
{
    int idx = blockIdx.x * blockDim.x + threadIdx.x;
    if (idx < E) {
        int pos = row_start[rows[idx]] + rank[idx];
        epk[pos] = int2{cols[idx], __float_as_int(vals[idx])};
    } else {
        int i = (idx - E) * 4;
        int castN = n0 + n1 + n2 + n3;
        if (i >= castN) return;
        const float* s; short* d;
        if (i < n0) { s = s0; d = d0; }
        else if ((i -= n0) < n1) { s = s1; d = d1; }
        else if ((i -= n1) < n2) { s = s2; d = d2; }
        else { i -= n2; s = s3; d = d3; }
        float4 v = *(const float4*)(s + i);
        *(short4*)(d + i) = short4{f2bf(v.x), f2bf(v.y), f2bf(v.z), f2bf(v.w)};
    }
}

// ================= quad-packed gather SpMM (C=128) =================
// 4 edges per wave-wide VMEM instruction: lane group g=lane>>4 owns edge j+4b+g,
// each lane loads uint4 (16B); 16 lanes cover one 256B row. Gather measured
// instruction-count-bound (C=128 and C=256 equal dur at 2x bytes), so 1/4 the
// instructions at equal bytes. Each lane holds ONE edge descriptor (no-spill
// form). Folds: shfl_xor 16 then 32.
template<int B>
static __device__ __forceinline__ void quad_batch(
    const unsigned* __restrict__ Hb, const int2* __restrict__ epk,
    int j, int sel, int loff, f32x2* acc)
{
    int2 e[B];
    #pragma unroll
    for (int b = 0; b < B; ++b) e[b] = epk[j + 4 * b + sel];
    uint4 g[B];
    #pragma unroll
    for (int b = 0; b < B; ++b)
        g[b] = *(const uint4*)(Hb + (size_t)e[b].x * 64 + loff);
    #pragma unroll
    for (int b = 0; b < B; ++b) {
        const float v = __int_as_float(e[b].y);
        acc[0] += v * bfpair(g[b].x);
        acc[1] += v * bfpair(g[b].y);
        acc[2] += v * bfpair(g[b].z);
        acc[3] += v * bfpair(g[b].w);
    }
}

// MODE 0: write bf16 row [N,128]. MODE 2: +bias, L2-normalize, write fp32 row.
template<int MODE>
__global__ __launch_bounds__(256) void spmm_gather_q(
    const short* __restrict__ H, const int* __restrict__ row_start,
    const int2* __restrict__ epk, void* __restrict__ outv,
    const float* __restrict__ bias, int N)
{
    const int wid = threadIdx.x >> 6;
    const int lane = threadIdx.x & 63;
    const int sel = lane >> 4;          // 0..3: which edge of the quad
    const int l15 = lane & 15;
    const int loff = l15 * 4;           // unsigned units; 16 lanes x 4 = 64 = full row
    const int row = blockIdx.x * 4 + wid;
    if (row >= N) return;
    int j = row_start[row];
    const int end = row_start[row + 1];
    const unsigned* Hb = (const unsigned*)H;

    f32x2 acc[4] = {};

    for (; j + 16 <= end; j += 16) quad_batch<4>(Hb, epk, j, sel, loff, acc);
    for (; j + 4 <= end; j += 4)   quad_batch<1>(Hb, epk, j, sel, loff, acc);
    if (j < end) {
        const int rem = end - j;        // 1..3 leftover edges; extra groups weight 0
        int2 e = epk[j + (sel < rem ? sel : rem - 1)];
        uint4 g = *(const uint4*)(Hb + (size_t)e.x * 64 + loff);
        const float v = (sel < rem) ? __int_as_float(e.y) : 0.f;
        acc[0] += v * bfpair(g.x);
        acc[1] += v * bfpair(g.y);
        acc[2] += v * bfpair(g.z);
        acc[3] += v * bfpair(g.w);
    }

    // fold the 4 edge-group partial sums
    #pragma unroll
    for (int u = 0; u < 4; ++u) {
        acc[u].x += __shfl_xor(acc[u].x, 16);
        acc[u].y += __shfl_xor(acc[u].y, 16);
        acc[u].x += __shfl_xor(acc[u].x, 32);
        acc[u].y += __shfl_xor(acc[u].y, 32);
    }

    if constexpr (MODE == 0) {
        if (lane < 16) {
            unsigned od[4];
            #pragma unroll
            for (int u = 0; u < 4; ++u)
                od[u] = (unsigned)(unsigned short)f2bf(acc[u].x)
                      | ((unsigned)(unsigned short)f2bf(acc[u].y) << 16);
            *(uint4*)((unsigned*)outv + (size_t)row * 64 + loff) =
                uint4{od[0], od[1], od[2], od[3]};
        }
    } else {
        const int c0 = l15 * 8;         // 8 channels per lane
        float4 b0 = *(const float4*)(bias + c0);
        float4 b1 = *(const float4*)(bias + c0 + 4);
        float o0 = acc[0].x + b0.x, o1 = acc[0].y + b0.y;
        float o2 = acc[1].x + b0.z, o3 = acc[1].y + b0.w;
        float o4 = acc[2].x + b1.x, o5 = acc[2].y + b1.y;
        float o6 = acc[3].x + b1.z, o7 = acc[3].y + b1.w;
        float ss = o0*o0 + o1*o1 + o2*o2 + o3*o3 + o4*o4 + o5*o5 + o6*o6 + o7*o7;
        #pragma unroll
        for (int d = 1; d < 16; d <<= 1)
            ss += __shfl_xor(ss, d);
        float s = 1.0f / fmaxf(sqrtf(ss), 1e-12f);
        if (lane < 16) {
            float* orow = (float*)outv + (size_t)row * 128 + c0;
            *(float4*)orow       = float4{o0 * s, o1 * s, o2 * s, o3 * s};
            *(float4*)(orow + 4) = float4{o4 * s, o5 * s, o6 * s, o7 * s};
        }
    }
}

// ================= pair-packed gather SpMM (C=256, MODE 0) =================
// 2 edges per wave-wide VMEM instruction: half-wave h=lane>>5 owns edge j+2b+h,
// each lane loads uint4 (16B); 32 lanes cover one 512B row. Fold: shfl_xor 32.
template<int B>
static __device__ __forceinline__ void pair256_batch(
    const unsigned* __restrict__ Hb, const int2* __restrict__ epk,
    int j, int sel, int loff, f32x2* acc)
{
    int2 e[B];
    #pragma unroll
    for (int b = 0; b < B; ++b) e[b] = epk[j + 2 * b + sel];
    uint4 g[B];
    #pragma unroll
    for (int b = 0; b < B; ++b)
        g[b] = *(const uint4*)(Hb + (size_t)e[b].x * 128 + loff);
    #pragma unroll
    for (int b = 0; b < B; ++b) {
        const float v = __int_as_float(e[b].y);
        acc[0] += v * bfpair(g[b].x);
        acc[1] += v * bfpair(g[b].y);
        acc[2] += v * bfpair(g[b].z);
        acc[3] += v * bfpair(g[b].w);
    }
}

__global__ __launch_bounds__(256) void spmm_gather_p256(
    const short* __restrict__ H, const int* __restrict__ row_start,
    const int2* __restrict__ epk, void* __restrict__ outv, int N)
{
    const int wid = threadIdx.x >> 6;
    const int lane = threadIdx.x & 63;
    const int sel = lane >> 5;          // 0: even edge, 1: odd edge
    const int l31 = lane & 31;
    const int loff = l31 * 4;           // 32 lanes x 4 unsigneds = 128 = full row
    const int row = blockIdx.x * 4 + wid;
    if (row >= N) return;
    int j = row_start[row];
    const int end = row_start[row + 1];
    const unsigned* Hb = (const unsigned*)H;

    f32x2 acc[4] = {};

    for (; j + 8 <= end; j += 8) pair256_batch<4>(Hb, epk, j, sel, loff, acc);
    for (; j + 2 <= end; j += 2) pair256_batch<1>(Hb, epk, j, sel, loff, acc);
    if (j < end) {
        int2 e = epk[j];
        uint4 g = *(const uint4*)(Hb + (size_t)e.x * 128 + loff);
        const float v = sel ? 0.f : __int_as_float(e.y);
        acc[0] += v * bfpair(g.x);
        acc[1] += v * bfpair(g.y);
        acc[2] += v * bfpair(g.z);
        acc[3] += v * bfpair(g.w);
    }

    #pragma unroll
    for (int u = 0; u < 4; ++u) {
        acc[u].x += __shfl_xor(acc[u].x, 32);
        acc[u].y += __shfl_xor(acc[u].y, 32);
    }

    if (lane < 32) {
        unsigned od[4];
        #pragma unroll
        for (int u = 0; u < 4; ++u)
            od[u] = (unsigned)(unsigned short)f2bf(acc[u].x)
                  | ((unsigned)(unsigned short)f2bf(acc[u].y) << 16);
        *(uint4*)((unsigned*)outv + (size_t)row * 128 + loff) =
            uint4{od[0], od[1], od[2], od[3]};
    }
}

// ================= bf16 MFMA GEMM, 128x64 tile, XCD-aware swizzle =================
// (round-0 proven dense path)
template<int K, int M, bool RELU, bool BIAS>
__global__ __launch_bounds__(256) void gemm_bf16(
    const short* __restrict__ A, const short* __restrict__ W,
    const float* __restrict__ bias, short* __restrict__ Y, int N)
{
    constexpr int MBLK = M / 64;
    constexpr int BK = 32;
    constexpr int PAD = 8;
    __shared__ short As[128][BK + PAD];
    __shared__ short Ws[64][BK + PAD];

    const int id = blockIdx.x;
    const int bx = (id / (8 * MBLK)) * 8 + (id & 7);
    const int by = (id >> 3) & (MBLK - 1);

    const int tid = threadIdx.x;
    const int wid = tid >> 6;
    const int lane = tid & 63;
    const int wm = wid & 1;
    const int wn = wid >> 1;
    const int l15 = lane & 15;
    const int quad = lane >> 4;
    const int bn = bx * 128;
    const int bm = by * 64;

    f32x4 acc[4][2] = {};

    for (int k0 = 0; k0 < K; k0 += BK) {
        #pragma unroll
        for (int c = 0; c < 2; ++c) {
            int chunk = tid + c * 256;
            int row = chunk >> 2;
            int koff = (chunk & 3) * 8;
            int gr = bn + row;
            ulonglong2 v = {0ull, 0ull};
            if (gr < N) v = *(const ulonglong2*)(A + (size_t)gr * K + k0 + koff);
            *(ulonglong2*)&As[row][koff] = v;
        }
        {
            int row = tid >> 2;
            int koff = (tid & 3) * 8;
            ulonglong2 v = *(const ulonglong2*)(W + (size_t)(bm + row) * K + k0 + koff);
            *(ulonglong2*)&Ws[row][koff] = v;
        }
        __syncthreads();

        bf16x8 aF[4], bF[2];
        #pragma unroll
        for (int mt = 0; mt < 4; ++mt)
            aF[mt] = *(const bf16x8*)&As[wm * 64 + mt * 16 + l15][quad * 8];
        #pragma unroll
        for (int nt = 0; nt < 2; ++nt)
            bF[nt] = *(const bf16x8*)&Ws[wn * 32 + nt * 16 + l15][quad * 8];

        #pragma unroll
        for (int mt = 0; mt < 4; ++mt)
            #pragma unroll
            for (int nt = 0; nt < 2; ++nt)
                acc[mt][nt] = __builtin_amdgcn_mfma_f32_16x16x32_bf16(
                    aF[mt], bF[nt], acc[mt][nt], 0, 0, 0);
        __syncthreads();
    }

    #pragma unroll
    for (int nt = 0; nt < 2; ++nt) {
        int col = bm + wn * 32 + nt * 16 + l15;
        float bv = BIAS ? bias[col] : 0.f;
        #pragma unroll
        for (int mt = 0; mt < 4; ++mt) {
            int row0 = bn + wm * 64 + mt * 16 + quad * 4;
            #pragma unroll
            for (int r = 0; r < 4; ++r) {
                int row = row0 + r;
                if (row < N) {
                    float v = acc[mt][nt][r] + bv;
                    if (RELU) v = fmaxf(v, 0.f);
                    Y[(size_t)row * M + col] = f2bf(v);
                }
            }
        }
    }
}

extern "C" void kernel_launch(void* const* d_in, const int* in_sizes, int n_in,
                              void* d_out, int out_size, void* d_ws, size_t ws_size,
                              hipStream_t stream) {
    const float* x        = (const float*)d_in[0];
    const int*   edge_row = (const int*)d_in[1];
    const int*   edge_col = (const int*)d_in[2];
    const float* edge_val = (const float*)d_in[3];
    const float* W1       = (const float*)d_in[4];
    const float* b1       = (const float*)d_in[5];
    const float* W2       = (const float*)d_in[6];
    const float* b2       = (const float*)d_in[7];
    const float* W3       = (const float*)d_in[8];
    const float* b3       = (const float*)d_in[9];
    float* out = (float*)d_out;

    const int N = N_NODES, E = N_EDGES;
    const int NB = (N + SCAN_ELEMS - 1) / SCAN_ELEMS;   // 98

    // workspace layout (round-0 scheme)
    short* xbf = (short*)d_ws;                    // [N,128] bf16
    short* Hbf = xbf + (size_t)N * IN_C;          // [N,256] bf16 (spmm outputs / H3)
    short* Gbf = Hbf + (size_t)N * HID_C;         // [N,256] bf16
    short* W1b = Gbf + (size_t)N * HID_C;         // [256,128]
    short* W2b = W1b + HID_C * IN_C;              // [256,256]
    short* W3b = W2b + HID_C * HID_C;             // [128,256]
    int* deg = (int*)(((uintptr_t)(W3b + OUT_C * HID_C) + 15) & ~(uintptr_t)15);
    int* row_start = deg + N;                     // [N+1]
    int* rank      = row_start + (N + 1);         // [E]
    int* bsum      = rank + E;                    // [128]
    int2* epk      = (int2*)(((uintptr_t)(bsum + 128) + 15) & ~(uintptr_t)15);  // [E]

    // ---- build CSR (atomic-free scatter) + casts ----
    hipMemsetAsync(deg, 0, N * sizeof(int), stream);
    hist_rank<<<(E + 255) / 256, 256, 0, stream>>>(edge_row, deg, rank, E);
    scan1<<<NB, SCAN_BLOCK, 0, stream>>>(deg, row_start, bsum, N);
    scan3<<<(N + 256) / 256, 256, 0, stream>>>(row_start, bsum, NB, N, E);
    {
        int n0 = N * IN_C, n1 = HID_C * IN_C, n2 = HID_C * HID_C, n3 = OUT_C * HID_C;
        int total = E + (n0 + n1 + n2 + n3) / 4;   // both parts wave-aligned
        scatter_cast<<<(total + 255) / 256, 256, 0, stream>>>(
            edge_row, edge_col, edge_val, row_start, rank, epk, E,
            x, xbf, n0, W1, W1b, n1, W2, W2b, n2, W3, W3b, n3);
    }

    const int spmm_grid = (N + 3) / 4;
    const int GXP = ((N + 127) / 128 + 7) & ~7;   // padded strips (OOB guarded)

    // Layer 1: Hbf = spmm(xbf) [N,128] (quad-packed); Gbf = relu(Hbf@W1.T+b1)
    spmm_gather_q<0><<<spmm_grid, 256, 0, stream>>>(
        xbf, row_start, epk, Hbf, nullptr, N);
    gemm_bf16<IN_C, HID_C, true, true><<<GXP * (HID_C / 64), 256, 0, stream>>>(
        Hbf, W1b, b1, Gbf, N);

    // Layer 2: Hbf = spmm(Gbf) [N,256] (pair-packed); Gbf = relu(Hbf@W2.T+b2)
    spmm_gather_p256<<<spmm_grid, 256, 0, stream>>>(
        Gbf, row_start, epk, Hbf, N);
    gemm_bf16<HID_C, HID_C, true, true><<<GXP * (HID_C / 64), 256, 0, stream>>>(
        Hbf, W2b, b2, Gbf, N);

    // Layer 3: Hbf = Gbf@W3.T [N,128]; out = normalize(spmm(Hbf) + b3) (quad)
    gemm_bf16<HID_C, OUT_C, false, false><<<GXP * (OUT_C / 64), 256, 0, stream>>>(
        Gbf, W3b, nullptr, Hbf, N);
    spmm_gather_q<2><<<spmm_grid, 256, 0, stream>>>(
        Hbf, row_start, epk, out, b3, N);
}